// Round 5
// baseline (1635.846 us; speedup 1.0000x reference)
//
#include <hip/hip_runtime.h>
#include <math.h>

#define T_ 256
#define B_ 32
#define E_ 256
#define HD_ 256
#define NG_ 1024
#define K_ 12
#define START_ 10
#define STOP_ 11
#define NEG_ -10000.0f
#define MAGICU 0x40000000u   // 2.0f — |h|<1 so h can never be this bit pattern
#define ISM(x) (__float_as_uint(x) == MAGICU)

typedef float f4_t __attribute__((ext_vector_type(4)));

__device__ __forceinline__ float sigf(float x) { return 1.0f / (1.0f + expf(-x)); }

// ---------- token gather (bwd dir reversed within each sequence length) ----------
__global__ void tok_gather(const int* __restrict__ sent, const int* __restrict__ lens,
                           int* __restrict__ tokA) {
    int e = blockIdx.x * 256 + threadIdx.x;      // 0..16383 = [dir][t*32+b]
    int dir = e >> 13, m = e & 8191, t = m >> 5, b = m & 31;
    int len = lens[b];
    int tt = dir ? (t < len ? len - 1 - t : t) : t;
    tokA[e] = sent[b * T_ + tt];
}

// ---------- Whh^T into [dir][k][u*4+gate] (unit-major gate packing) ----------
__global__ void whh_tr(const float* __restrict__ Wf, const float* __restrict__ Wb,
                       float* __restrict__ WT) {
    int dir = blockIdx.x >> 8, k = blockIdx.x & 255, u = threadIdx.x;
    const float* W = dir ? Wb : Wf;
    float4 v;
    v.x = W[(0 * HD_ + u) * HD_ + k];   // i
    v.y = W[(1 * HD_ + u) * HD_ + k];   // f
    v.z = W[(2 * HD_ + u) * HD_ + k];   // g
    v.w = W[(3 * HD_ + u) * HD_ + k];   // o
    ((float4*)(WT + ((size_t)dir * 256 + k) * NG_))[u] = v;
}

// ---------- fill the h-exchange ring with the MAGIC sentinel ----------
__global__ void hex_init(float* __restrict__ hex) {
    int i = blockIdx.x * 256 + threadIdx.x;      // 4096 blocks -> 16 MB
    float4 m = make_float4(2.0f, 2.0f, 2.0f, 2.0f);
    ((float4*)hex)[i] = m;
}

// ---------- fused embedding-gather + input GEMM: G[dir][t*32+b][u*4+g] = x@Wih^T + bih + bhh ----------
__global__ __launch_bounds__(256) void in_gemm(
    const float* __restrict__ emb, const int* __restrict__ tokA,
    const float* __restrict__ Wih_f, const float* __restrict__ Wih_b,
    const float* __restrict__ bih_f, const float* __restrict__ bhh_f,
    const float* __restrict__ bih_b, const float* __restrict__ bhh_b,
    float* __restrict__ G) {
    const int dir = blockIdx.z;
    const int n0 = blockIdx.x * 128, m0 = blockIdx.y * 128;
    const float* Wih = dir ? Wih_b : Wih_f;
    const float* bihp = dir ? bih_b : bih_f;
    const float* bhhp = dir ? bhh_b : bhh_f;
    __shared__ float As[8][128];
    __shared__ float Bs[8][128];
    const int tid = threadIdx.x;
    const int rs = tid >> 1, kc = (tid & 1) * 4;
    const int tok = tokA[dir * 8192 + m0 + rs];
    const float* arow = emb + (size_t)tok * E_;
    const int np = n0 + rs;
    const int wrow = ((np & 3) << 8) | (np >> 2);     // permuted col n'=u*4+g -> Wih row g*256+u
    const float* brow = Wih + (size_t)wrow * E_;
    const int ty = tid >> 4, tx = tid & 15;

    float acc[8][8];
#pragma unroll
    for (int i = 0; i < 8; ++i)
#pragma unroll
        for (int j = 0; j < 8; ++j) acc[i][j] = 0.f;

    for (int k0 = 0; k0 < E_; k0 += 8) {
        float4 av = *(const float4*)(arow + k0 + kc);
        float4 bv = *(const float4*)(brow + k0 + kc);
        __syncthreads();
        As[kc + 0][rs] = av.x; As[kc + 1][rs] = av.y; As[kc + 2][rs] = av.z; As[kc + 3][rs] = av.w;
        Bs[kc + 0][rs] = bv.x; Bs[kc + 1][rs] = bv.y; Bs[kc + 2][rs] = bv.z; Bs[kc + 3][rs] = bv.w;
        __syncthreads();
#pragma unroll
        for (int k = 0; k < 8; ++k) {
            float4 a0 = *(const float4*)&As[k][ty * 8];
            float4 a1 = *(const float4*)&As[k][ty * 8 + 4];
            float4 b0 = *(const float4*)&Bs[k][tx * 8];
            float4 b1 = *(const float4*)&Bs[k][tx * 8 + 4];
            float af8[8] = {a0.x, a0.y, a0.z, a0.w, a1.x, a1.y, a1.z, a1.w};
            float bf8[8] = {b0.x, b0.y, b0.z, b0.w, b1.x, b1.y, b1.z, b1.w};
#pragma unroll
            for (int i = 0; i < 8; ++i)
#pragma unroll
                for (int j = 0; j < 8; ++j) acc[i][j] += af8[i] * bf8[j];
        }
    }
    float bias[8];
#pragma unroll
    for (int j = 0; j < 8; ++j) {
        int nn = n0 + tx * 8 + j;
        int wr = ((nn & 3) << 8) | (nn >> 2);
        bias[j] = bihp[wr] + bhhp[wr];
    }
#pragma unroll
    for (int i = 0; i < 8; ++i) {
        int m = m0 + ty * 8 + i;
        float* gp = G + ((size_t)dir * 8192 + m) * NG_ + n0 + tx * 8;
        float4 o0 = {acc[i][0] + bias[0], acc[i][1] + bias[1], acc[i][2] + bias[2], acc[i][3] + bias[3]};
        float4 o1 = {acc[i][4] + bias[4], acc[i][5] + bias[5], acc[i][6] + bias[6], acc[i][7] + bias[7]};
        *(float4*)gp = o0;
        *(float4*)(gp + 4) = o1;
    }
}

// ---------- recurrence v13: dir-merged. 64 WGs (bt*16+ut) x 512 thr; each WG
// owns 16 units of BOTH directions for its bt-group (8 batches). The two
// independent chains interleave per step: dir0 consume/FMA/act, then dir1 —
// each dir's publish->LLC->poll round trip is in flight during the OTHER dir's
// compute phase, taking the exchange off the critical path (r4 showed exchange,
// not FMA issue, dominates). All in-loop VMEM is inline asm ({pub, gp-load,
// pend-load} x2/step) so consume points use counted s_waitcnt vmcnt(3)
// (vmcnt(1) at last-step dir1); waits tie pend+gp as "+v" so uses can't hoist.
// Magic-sentinel poll remains the correctness net. Stage->FMA stays
// barrier-free (wave-private LDS rows); 4 barriers/step guard red4 only.
__global__ __launch_bounds__(512, 1) void lstm_recm(
    const float* __restrict__ WhhT, const float* __restrict__ G,
    const float* __restrict__ h0, const float* __restrict__ c0,
    const int* __restrict__ lens, float* __restrict__ hex) {
    const int wg = blockIdx.x;                   // bt*16 + ut
    const int bt = wg >> 4, ut = wg & 15;
    const int tid = threadIdx.x;
    const int wv = tid >> 6, ln = tid & 63;
    const int bh = wv >> 2, ksup = wv & 3;       // batch-half, k-quarter
    const int kssub = ln >> 4, u = ln & 15;      // k-sub, unit-in-tile
    const int ks = ksup * 4 + kssub;             // 16-k slice id (k in [ks*16,+16))
    const int gu = ut * 16 + u;                  // global unit index
    // staging lane map: this lane fetches h[sb][sk..sk+3]
    const int sb = bh * 4 + (ln & 3);
    const int sk = ksup * 64 + ((ln >> 2) & 15) * 4;
    const int x4 = (sk >> 4) & 3;                // LDS row-swizzle bits
    const int speer = sk >> 4;                   // producing WG (16-unit tiles) 0..15

    __shared__ float4 hsA4[256];                 // h[k][b0..3] (swizzled rows)
    __shared__ float4 hsB4[256];                 // h[k][b4..7]
    __shared__ float4 red4[512 * 5];             // partials: row=tid, rotated slots (40 KB)
    __shared__ float4 hT4[2][32];                // own h per dir: [b][16u] floats

    const int Tmax = lens[bt * 8];               // lens sorted desc -> group max

    // ---- W into registers: 16 f4/thread/dir ----
    const float4* WT4 = (const float4*)WhhT;
    float4 W0[16], W1[16];
#pragma unroll
    for (int j = 0; j < 16; ++j) {
        W0[j] = WT4[(ks * 16 + j) * 256 + gu];
        W1[j] = WT4[65536 + (ks * 16 + j) * 256 + gu];
    }

    const bool is_act = (ln < 16);               // act lane: batch=wv, unit=ln
    float cc0 = 0.f, cc1 = 0.f;
    f4_t gp0, gp1;
    const float* Gd0 = G;
    const float* Gd1 = G + (size_t)8192 * NG_;
    if (is_act) {
        cc0 = c0[(bt * 8 + wv) * HD_ + gu];
        cc1 = c0[(B_ + bt * 8 + wv) * HD_ + gu];
        gp0 = ((const f4_t*)(Gd0 + (size_t)(bt * 8 + wv) * NG_))[gu];
        gp1 = ((const f4_t*)(Gd1 + (size_t)(bt * 8 + wv) * NG_))[gu];
    }

    float* hexg0 = hex + (size_t)bt * T_ * 2048;        // fwd group [t][b*256+u]
    float* hexg1 = hex + (size_t)(4 + bt) * T_ * 2048;  // bwd group
    float4* hsX4 = bh ? hsB4 : hsA4;
    float* hsX = (float*)hsX4;

    f4_t pend0, pend1;

    for (int t = 0; t < Tmax; ++t) {
        // ======================= dir 0 =======================
        {
            float4 hv;
            if (t == 0) {
                hv = *(const float4*)(h0 + (size_t)(bt * 8 + sb) * HD_ + sk);
            } else if (speer == ut) {
                hv = hT4[0][sb * 4 + ((sk & 15) >> 2)];
            } else {
                asm volatile("s_waitcnt vmcnt(3)" : "+v"(pend0), "+v"(gp0) :: "memory");
                hv.x = pend0.x; hv.y = pend0.y; hv.z = pend0.z; hv.w = pend0.w;
                if (ISM(hv.x) || ISM(hv.y) || ISM(hv.z) || ISM(hv.w)) {
                    const float* src = hexg0 + (size_t)(t - 1) * 2048 + sb * 256 + sk;
                    int it = 0;
                    for (;;) {
                        __builtin_amdgcn_s_sleep(1);
                        float a0 = __hip_atomic_load(src + 0, __ATOMIC_RELAXED, __HIP_MEMORY_SCOPE_AGENT);
                        float a1 = __hip_atomic_load(src + 1, __ATOMIC_RELAXED, __HIP_MEMORY_SCOPE_AGENT);
                        float a2 = __hip_atomic_load(src + 2, __ATOMIC_RELAXED, __HIP_MEMORY_SCOPE_AGENT);
                        float a3 = __hip_atomic_load(src + 3, __ATOMIC_RELAXED, __HIP_MEMORY_SCOPE_AGENT);
                        if (!(ISM(a0) || ISM(a1) || ISM(a2) || ISM(a3))) {
                            hv = make_float4(a0, a1, a2, a3); break;
                        }
                        if (++it > (1 << 22)) break;   // bail -> visible failure, not hang
                    }
                }
            }
            // stage into wave-private swizzled rows: logical row R -> R ^ ((R>>4)&3)
            hsX[(sk + (0 ^ x4)) * 4 + (ln & 3)] = hv.x;
            hsX[(sk + (1 ^ x4)) * 4 + (ln & 3)] = hv.y;
            hsX[(sk + (2 ^ x4)) * 4 + (ln & 3)] = hv.z;
            hsX[(sk + (3 ^ x4)) * 4 + (ln & 3)] = hv.w;
            asm volatile("s_waitcnt lgkmcnt(0)" ::: "memory");   // wave-local visibility

            // FMA: 1 unit x 4 gates x 4 batches x 16 k
            float4 A0 = {0,0,0,0}, A1 = {0,0,0,0}, A2 = {0,0,0,0}, A3 = {0,0,0,0};
#pragma unroll
            for (int j = 0; j < 16; ++j) {
                float4 h4 = hsX4[ks * 16 + (j ^ kssub)];
                float4 w4 = W0[j];
                A0.x += w4.x*h4.x; A0.y += w4.y*h4.x; A0.z += w4.z*h4.x; A0.w += w4.w*h4.x;
                A1.x += w4.x*h4.y; A1.y += w4.y*h4.y; A1.z += w4.z*h4.y; A1.w += w4.w*h4.y;
                A2.x += w4.x*h4.z; A2.y += w4.y*h4.z; A2.z += w4.z*h4.z; A2.w += w4.w*h4.z;
                A3.x += w4.x*h4.w; A3.y += w4.y*h4.w; A3.z += w4.z*h4.w; A3.w += w4.w*h4.w;
            }
            float4* r = &red4[tid * 5];
            r[(0 + kssub) & 3] = A0; r[(1 + kssub) & 3] = A1;
            r[(2 + kssub) & 3] = A2; r[(3 + kssub) & 3] = A3;
        }
        asm volatile("s_waitcnt lgkmcnt(0)\n\ts_barrier" ::: "memory");   // barrier A
        if (is_act) {
            const int b = wv, bq = b & 3, bhv = b >> 2;
            float si = gp0.x, sf = gp0.y, sg = gp0.z, so = gp0.w;
#pragma unroll
            for (int k2 = 0; k2 < 4; ++k2)
#pragma unroll
                for (int k3 = 0; k3 < 4; ++k3) {
                    int tid2 = (bhv * 4 + k2) * 64 + k3 * 16 + ln;
                    float4 p = red4[tid2 * 5 + ((bq + k3) & 3)];
                    si += p.x; sf += p.y; sg += p.z; so += p.w;
                }
            cc0 = sigf(sf) * cc0 + sigf(si) * tanhf(sg);
            float h = sigf(so) * tanhf(cc0);
            ((float*)hT4[0])[b * 16 + ln] = h;
            float* dst = hexg0 + (size_t)t * 2048 + b * 256 + gu;
            asm volatile("global_store_dword %0, %1, off sc0 sc1" :: "v"(dst), "v"(h) : "memory");
            if (t + 1 < Tmax) {
                const float* gsrc = Gd0 + ((size_t)(t + 1) * B_ + bt * 8 + b) * NG_ + (size_t)gu * 4;
                asm volatile("global_load_dwordx4 %0, %1, off" : "=v"(gp0) : "v"(gsrc) : "memory");
            }
        }
        if (t + 1 < Tmax && speer != ut) {
            const float* nsrc = hexg0 + (size_t)t * 2048 + sb * 256 + sk;
            asm volatile("global_load_dwordx4 %0, %1, off sc0 sc1"
                         : "=v"(pend0) : "v"(nsrc) : "memory");
        }
        asm volatile("s_waitcnt lgkmcnt(0)\n\ts_barrier" ::: "memory");   // barrier B

        // ======================= dir 1 =======================
        {
            float4 hv;
            if (t == 0) {
                hv = *(const float4*)(h0 + (size_t)(B_ + bt * 8 + sb) * HD_ + sk);
            } else if (speer == ut) {
                hv = hT4[1][sb * 4 + ((sk & 15) >> 2)];
            } else {
                if (t + 1 < Tmax)
                    asm volatile("s_waitcnt vmcnt(3)" : "+v"(pend1), "+v"(gp1) :: "memory");
                else
                    asm volatile("s_waitcnt vmcnt(1)" : "+v"(pend1), "+v"(gp1) :: "memory");
                hv.x = pend1.x; hv.y = pend1.y; hv.z = pend1.z; hv.w = pend1.w;
                if (ISM(hv.x) || ISM(hv.y) || ISM(hv.z) || ISM(hv.w)) {
                    const float* src = hexg1 + (size_t)(t - 1) * 2048 + sb * 256 + sk;
                    int it = 0;
                    for (;;) {
                        __builtin_amdgcn_s_sleep(1);
                        float a0 = __hip_atomic_load(src + 0, __ATOMIC_RELAXED, __HIP_MEMORY_SCOPE_AGENT);
                        float a1 = __hip_atomic_load(src + 1, __ATOMIC_RELAXED, __HIP_MEMORY_SCOPE_AGENT);
                        float a2 = __hip_atomic_load(src + 2, __ATOMIC_RELAXED, __HIP_MEMORY_SCOPE_AGENT);
                        float a3 = __hip_atomic_load(src + 3, __ATOMIC_RELAXED, __HIP_MEMORY_SCOPE_AGENT);
                        if (!(ISM(a0) || ISM(a1) || ISM(a2) || ISM(a3))) {
                            hv = make_float4(a0, a1, a2, a3); break;
                        }
                        if (++it > (1 << 22)) break;
                    }
                }
            }
            hsX[(sk + (0 ^ x4)) * 4 + (ln & 3)] = hv.x;
            hsX[(sk + (1 ^ x4)) * 4 + (ln & 3)] = hv.y;
            hsX[(sk + (2 ^ x4)) * 4 + (ln & 3)] = hv.z;
            hsX[(sk + (3 ^ x4)) * 4 + (ln & 3)] = hv.w;
            asm volatile("s_waitcnt lgkmcnt(0)" ::: "memory");

            float4 A0 = {0,0,0,0}, A1 = {0,0,0,0}, A2 = {0,0,0,0}, A3 = {0,0,0,0};
#pragma unroll
            for (int j = 0; j < 16; ++j) {
                float4 h4 = hsX4[ks * 16 + (j ^ kssub)];
                float4 w4 = W1[j];
                A0.x += w4.x*h4.x; A0.y += w4.y*h4.x; A0.z += w4.z*h4.x; A0.w += w4.w*h4.x;
                A1.x += w4.x*h4.y; A1.y += w4.y*h4.y; A1.z += w4.z*h4.y; A1.w += w4.w*h4.y;
                A2.x += w4.x*h4.z; A2.y += w4.y*h4.z; A2.z += w4.z*h4.z; A2.w += w4.w*h4.z;
                A3.x += w4.x*h4.w; A3.y += w4.y*h4.w; A3.z += w4.z*h4.w; A3.w += w4.w*h4.w;
            }
            float4* r = &red4[tid * 5];
            r[(0 + kssub) & 3] = A0; r[(1 + kssub) & 3] = A1;
            r[(2 + kssub) & 3] = A2; r[(3 + kssub) & 3] = A3;
        }
        asm volatile("s_waitcnt lgkmcnt(0)\n\ts_barrier" ::: "memory");   // barrier C
        if (is_act) {
            const int b = wv, bq = b & 3, bhv = b >> 2;
            float si = gp1.x, sf = gp1.y, sg = gp1.z, so = gp1.w;
#pragma unroll
            for (int k2 = 0; k2 < 4; ++k2)
#pragma unroll
                for (int k3 = 0; k3 < 4; ++k3) {
                    int tid2 = (bhv * 4 + k2) * 64 + k3 * 16 + ln;
                    float4 p = red4[tid2 * 5 + ((bq + k3) & 3)];
                    si += p.x; sf += p.y; sg += p.z; so += p.w;
                }
            cc1 = sigf(sf) * cc1 + sigf(si) * tanhf(sg);
            float h = sigf(so) * tanhf(cc1);
            ((float*)hT4[1])[b * 16 + ln] = h;
            float* dst = hexg1 + (size_t)t * 2048 + b * 256 + gu;
            asm volatile("global_store_dword %0, %1, off sc0 sc1" :: "v"(dst), "v"(h) : "memory");
            if (t + 1 < Tmax) {
                const float* gsrc = Gd1 + ((size_t)(t + 1) * B_ + bt * 8 + b) * NG_ + (size_t)gu * 4;
                asm volatile("global_load_dwordx4 %0, %1, off" : "=v"(gp1) : "v"(gsrc) : "memory");
            }
        }
        if (t + 1 < Tmax && speer != ut) {
            const float* nsrc = hexg1 + (size_t)t * 2048 + sb * 256 + sk;
            asm volatile("global_load_dwordx4 %0, %1, off sc0 sc1"
                         : "=v"(pend1) : "v"(nsrc) : "memory");
        }
        asm volatile("s_waitcnt lgkmcnt(0)\n\ts_barrier" ::: "memory");   // barrier D
    }
}

// ---------- features from hex: feats[b*T+t][k] = hcat . W_out[k] + b_out[k] ----------
__global__ void feat_k(const float* __restrict__ hex, const int* __restrict__ lens,
                       const float* __restrict__ Wout, const float* __restrict__ bout,
                       float* __restrict__ feats) {
    int tid = threadIdx.x;                 // 192 = 16 pos x 12 tags
    int pl = tid / 12, k = tid % 12;
    int p = blockIdx.x * 16 + pl;          // p = b*256 + t
    int b = p >> 8, t = p & 255;
    int len = lens[b];
    int tr = t < len ? len - 1 - t : t;    // bwd un-reversal (packed semantics)
    const float4* hf = (const float4*)(hex + ((size_t)(b >> 3) * T_ + t) * 2048 + (b & 7) * 256);
    const float4* hb = (const float4*)(hex + ((size_t)(4 + (b >> 3)) * T_ + tr) * 2048 + (b & 7) * 256);
    const float4* w0 = (const float4*)(Wout + (size_t)k * 512);
    const float4* w1 = (const float4*)(Wout + (size_t)k * 512 + 256);
    float acc = bout[k];
#pragma unroll 4
    for (int j = 0; j < 64; ++j) {
        float4 h4 = hf[j], v4 = w0[j];
        acc += h4.x * v4.x + h4.y * v4.y + h4.z * v4.z + h4.w * v4.w;
    }
#pragma unroll 4
    for (int j = 0; j < 64; ++j) {
        float4 h4 = hb[j], v4 = w1[j];
        acc += h4.x * v4.x + h4.y * v4.y + h4.z * v4.z + h4.w * v4.w;
    }
    feats[(size_t)p * K_ + k] = acc;
}

// ---------- Viterbi + backtrace: single block, feats prefetch, bp nibble-packed ----------
__global__ __launch_bounds__(512) void viterbi_k(
    const float* __restrict__ feats, const float* __restrict__ trans,
    const int* __restrict__ lens, float* __restrict__ out) {
    __shared__ float fv[2][B_][16];
    __shared__ float tl[K_][16];
    __shared__ unsigned char bp[T_][B_][6];    // 4-bit backpointers, 48KB
    __shared__ int best_last[B_];
    int tid = threadIdx.x;
    int b = tid >> 4, lane = tid & 15;
    if (tid < K_ * K_) tl[tid / 12][tid % 12] = trans[tid];
    if (lane < K_) fv[0][b][lane] = (lane == START_) ? 0.f : NEG_;
    __syncthreads();
    int len = lens[b];
    int pp = 0;
    float f_cur = 0.f;
    if (lane < K_) f_cur = feats[(size_t)b * T_ * K_ + lane];
    for (int t = 0; t < T_; ++t) {
        float f_nxt = 0.f;                       // prefetch t+1 before the compute chain
        if (t + 1 < T_ && lane < K_) f_nxt = feats[((size_t)b * T_ + t + 1) * K_ + lane];
        if (lane < K_) {
            float best = fv[pp][b][0] + tl[lane][0];
            int argp = 0;
#pragma unroll
            for (int p = 1; p < K_; ++p) {
                float v = fv[pp][b][p] + tl[lane][p];
                if (v > best) { best = v; argp = p; }   // strict > = first-max (matches jnp.argmax)
            }
            float nb = best + f_cur;
            fv[pp ^ 1][b][lane] = (t < len) ? nb : fv[pp][b][lane];
            int other = __shfl_xor(argp, 1);
            if ((lane & 1) == 0) bp[t][b][lane >> 1] = (unsigned char)(argp | (other << 4));
        }
        __syncthreads();
        pp ^= 1;
        f_cur = f_nxt;
    }
    if (lane == 0) {
        float best = fv[pp][b][0] + tl[STOP_][0];
        int bl = 0;
#pragma unroll
        for (int p = 1; p < K_; ++p) {
            float v = fv[pp][b][p] + tl[STOP_][p];
            if (v > best) { best = v; bl = p; }
        }
        out[b] = best;
        best_last[b] = bl;
    }
    __syncthreads();
    if (lane == 0) {
        int tag = best_last[b];
        for (int t = T_ - 1; t >= 0; --t) {
            int m = (t < len);
            out[B_ + b * T_ + t] = (float)(m ? tag : -1);
            if (m) tag = (bp[t][b][tag >> 1] >> ((tag & 1) * 4)) & 15;
        }
    }
}

extern "C" void kernel_launch(void* const* d_in, const int* in_sizes, int n_in,
                              void* d_out, int out_size, void* d_ws, size_t ws_size,
                              hipStream_t stream) {
    const int*   sent  = (const int*)d_in[0];
    const int*   lens  = (const int*)d_in[1];
    const float* emb   = (const float*)d_in[2];
    const float* Wih_f = (const float*)d_in[3];
    const float* Whh_f = (const float*)d_in[4];
    const float* bih_f = (const float*)d_in[5];
    const float* bhh_f = (const float*)d_in[6];
    const float* Wih_b = (const float*)d_in[7];
    const float* Whh_b = (const float*)d_in[8];
    const float* bih_b = (const float*)d_in[9];
    const float* bhh_b = (const float*)d_in[10];
    const float* h0    = (const float*)d_in[11];
    const float* c0    = (const float*)d_in[12];
    const float* Wout  = (const float*)d_in[13];
    const float* bout  = (const float*)d_in[14];
    const float* trans = (const float*)d_in[15];
    float* out = (float*)d_out;

    char* ws = (char*)d_ws;
    int*   tokA  = (int*)ws;                                  // 64 KB
    float* WhhT  = (float*)(ws + 65536);                      // 2 MB
    float* G     = (float*)(ws + 2162688);                    // 67.1 MB
    float* feats = (float*)(ws + 69271552);                   // 0.39 MB
    float* hex   = (float*)(ws + 69664768);                   // 16 MB  [8 groups][T][2048]

    tok_gather<<<64, 256, 0, stream>>>(sent, lens, tokA);
    whh_tr<<<512, 256, 0, stream>>>(Whh_f, Whh_b, WhhT);
    hex_init<<<4096, 256, 0, stream>>>(hex);
    in_gemm<<<dim3(8, 64, 2), 256, 0, stream>>>(emb, tokA, Wih_f, Wih_b,
                                                bih_f, bhh_f, bih_b, bhh_b, G);
    lstm_recm<<<64, 512, 0, stream>>>(WhhT, G, h0, c0, lens, hex);
    feat_k<<<512, 192, 0, stream>>>(hex, lens, Wout, bout, feats);
    viterbi_k<<<1, 512, 0, stream>>>(feats, trans, lens, out);
}

// Round 6
// 1112.308 us; speedup vs baseline: 1.4707x; 1.4707x over previous
//
#include <hip/hip_runtime.h>
#include <math.h>

#define T_ 256
#define B_ 32
#define E_ 256
#define HD_ 256
#define NG_ 1024
#define K_ 12
#define START_ 10
#define STOP_ 11
#define NEG_ -10000.0f
#define MAGICU 0x40000000u   // 2.0f — |h|<1 so h can never be this bit pattern

typedef float f4_t __attribute__((ext_vector_type(4)));

__device__ __forceinline__ float sigf(float x) { return 1.0f / (1.0f + expf(-x)); }

// ---------- fused prep: hex sentinel fill + Whh^T + token gather + gcnt zero ----------
__global__ void prep(const int* __restrict__ sent, const int* __restrict__ lens,
                     int* __restrict__ tokA, const float* __restrict__ Wf,
                     const float* __restrict__ Wb, float* __restrict__ WT,
                     float* __restrict__ hex, int* __restrict__ gcnt) {
    const int b = blockIdx.x, tid = threadIdx.x;
    if (b < 4096) {
        // hex sentinel fill: 4096 blocks x 256 thr x 16 B = 16 MB
        float4 m = make_float4(2.0f, 2.0f, 2.0f, 2.0f);
        ((float4*)hex)[b * 256 + tid] = m;
    } else if (b < 4608) {
        // Whh^T into [dir][k][u*4+gate] (unit-major gate packing)
        int b2 = b - 4096;
        int dir = b2 >> 8, k = b2 & 255, u = tid;
        const float* W = dir ? Wb : Wf;
        float4 v;
        v.x = W[(0 * HD_ + u) * HD_ + k];   // i
        v.y = W[(1 * HD_ + u) * HD_ + k];   // f
        v.z = W[(2 * HD_ + u) * HD_ + k];   // g
        v.w = W[(3 * HD_ + u) * HD_ + k];   // o
        ((float4*)(WT + ((size_t)dir * 256 + k) * NG_))[u] = v;
    } else {
        // token gather (bwd dir reversed within each sequence length) + gcnt zero
        int e = (b - 4608) * 256 + tid;      // 0..16383 = [dir][t*32+b]
        if (e < 128) gcnt[e] = 0;
        int dir = e >> 13, m = e & 8191, t = m >> 5, bb = m & 31;
        int len = lens[bb];
        int tt = dir ? (t < len ? len - 1 - t : t) : t;
        tokA[e] = sent[bb * T_ + tt];
    }
}

// ---------- mega-kernel: blockIdx<64 = v11 recurrence; >=64 = in_gemm producer.
// One launch -> true concurrency on one stream. Producers write G with sc0 sc1
// stores + vmcnt(0) drain + barrier + release atomicAdd on gcnt[dir*64+by]
// (= the proven hex publish discipline); by covers t in [by*4, by*4+4).
// lstm gates its G prefetch on gcnt; on not-ready it SKIPS the prefetch (no
// stale L2 pull) and later polls + reloads via an LLC-coherent sc0 sc1 load.
// All spins carry bail counters -> no hang possible.
__global__ __launch_bounds__(512, 1) void mega(
    const float* __restrict__ emb, const int* __restrict__ tokA,
    const float* __restrict__ Wih_f, const float* __restrict__ Wih_b,
    const float* __restrict__ bih_f, const float* __restrict__ bhh_f,
    const float* __restrict__ bih_b, const float* __restrict__ bhh_b,
    const float* __restrict__ WhhT, float* __restrict__ G,
    const float* __restrict__ h0, const float* __restrict__ c0,
    const int* __restrict__ lens, float* __restrict__ hex,
    int* __restrict__ gcnt) {
    __shared__ float smem[24832];                // 99328 B, carved per role
    const int tid = threadIdx.x;

    if (blockIdx.x >= 64) {
        // ================= in_gemm role (512 threads, 128x128 tile) =================
        const int bi = blockIdx.x - 64;
        const int by = bi >> 4, sub = bi & 15;   // by-major order -> early t-tiles first
        const int dir = sub >> 3, bx = sub & 7;
        const int n0 = bx * 128, m0 = by * 128;
        float* As = smem;                        // [8][128]
        float* Bs = smem + 1024;                 // [8][128]
        const int rs = (tid & 255) >> 1, kc = (tid & 1) * 4;
        const float* srow;
        if (tid < 256) {
            int tok = tokA[dir * 8192 + m0 + rs];
            srow = emb + (size_t)tok * E_;
        } else {
            int np = n0 + rs;
            int wrow = ((np & 3) << 8) | (np >> 2);   // permuted col n'=u*4+g -> Wih row g*256+u
            srow = (dir ? Wih_b : Wih_f) + (size_t)wrow * E_;
        }
        float* Ls = (tid < 256) ? As : Bs;
        const int ty = tid >> 4, tx = tid & 15;  // ty 0..31 (4 rows), tx 0..15 (8 cols)

        float acc[4][8];
#pragma unroll
        for (int i = 0; i < 4; ++i)
#pragma unroll
            for (int j = 0; j < 8; ++j) acc[i][j] = 0.f;

        for (int k0 = 0; k0 < E_; k0 += 8) {
            float4 v = *(const float4*)(srow + k0 + kc);
            __syncthreads();
            Ls[(kc + 0) * 128 + rs] = v.x;
            Ls[(kc + 1) * 128 + rs] = v.y;
            Ls[(kc + 2) * 128 + rs] = v.z;
            Ls[(kc + 3) * 128 + rs] = v.w;
            __syncthreads();
#pragma unroll
            for (int k = 0; k < 8; ++k) {
                float4 a  = *(const float4*)&As[k * 128 + ty * 4];
                float4 b0 = *(const float4*)&Bs[k * 128 + tx * 8];
                float4 b1 = *(const float4*)&Bs[k * 128 + tx * 8 + 4];
                float af[4] = {a.x, a.y, a.z, a.w};
                float bf[8] = {b0.x, b0.y, b0.z, b0.w, b1.x, b1.y, b1.z, b1.w};
#pragma unroll
                for (int i = 0; i < 4; ++i)
#pragma unroll
                    for (int j = 0; j < 8; ++j) acc[i][j] += af[i] * bf[j];
            }
        }
        const float* bihp = dir ? bih_b : bih_f;
        const float* bhhp = dir ? bhh_b : bhh_f;
        float bias[8];
#pragma unroll
        for (int j = 0; j < 8; ++j) {
            int nn = n0 + tx * 8 + j;
            int wr = ((nn & 3) << 8) | (nn >> 2);
            bias[j] = bihp[wr] + bhhp[wr];
        }
#pragma unroll
        for (int i = 0; i < 4; ++i) {
            int m = m0 + ty * 4 + i;
            float* gp = G + ((size_t)dir * 8192 + m) * NG_ + n0 + tx * 8;
            f4_t o0, o1;
            o0.x = acc[i][0] + bias[0]; o0.y = acc[i][1] + bias[1];
            o0.z = acc[i][2] + bias[2]; o0.w = acc[i][3] + bias[3];
            o1.x = acc[i][4] + bias[4]; o1.y = acc[i][5] + bias[5];
            o1.z = acc[i][6] + bias[6]; o1.w = acc[i][7] + bias[7];
            asm volatile("global_store_dwordx4 %0, %1, off sc0 sc1" :: "v"(gp), "v"(o0) : "memory");
            asm volatile("global_store_dwordx4 %0, %1, off sc0 sc1" :: "v"(gp + 4), "v"(o1) : "memory");
        }
        asm volatile("s_waitcnt vmcnt(0)" ::: "memory");
        __syncthreads();
        if (tid == 0)
            __hip_atomic_fetch_add(gcnt + dir * 64 + by, 1, __ATOMIC_RELEASE, __HIP_MEMORY_SCOPE_AGENT);
        return;
    }

    // ================= lstm role: v11 verbatim + G-counter gating =================
    float4* red4 = (float4*)smem;                // 512*11 f4 (90112 B)
    float4* hsA4 = (float4*)(smem + 22528);      // 256 f4: h[k][b0..3]
    float4* hsB4 = (float4*)(smem + 23552);      // 256 f4: h[k][b4..7]
    float4* hT4  = (float4*)(smem + 24576);      // 64 f4: own h [b][32u]

    const int wg = blockIdx.x;                   // dir*32 + bt*8 + ut
    const int dir = wg >> 5, bt = (wg >> 3) & 3, ut = wg & 7;
    const int wv = tid >> 6, ln = tid & 63;
    const int upair = ln & 15;
    const int kssub = ln >> 4;
    const int ksup = wv >> 1, bh = wv & 1;
    const int ks = ksup * 4 + kssub;
    const int sb = bh * 4 + (ln & 3);
    const int sk = ksup * 64 + (ln >> 2) * 4;
    const int speer = sk >> 5;

    const int Tmax = lens[bt * 8];               // lens sorted desc -> group max

    // ---- W into registers: 32 f4/thread ----
    const float4* WT4 = (const float4*)(WhhT + (size_t)dir * 256 * NG_);
    const int gu_e = ut * 32 + upair * 2;
    float4 We[16], Wo[16];
#pragma unroll
    for (int j = 0; j < 16; ++j) {
        We[j] = WT4[(ks * 16 + j) * 256 + gu_e];
        Wo[j] = WT4[(ks * 16 + j) * 256 + gu_e + 1];
    }

    // ---- wait for G tile by=0 (t=0..3) before the initial gp load ----
    {
        int it = 0;
        while (__hip_atomic_load(gcnt + dir * 64, __ATOMIC_RELAXED, __HIP_MEMORY_SCOPE_AGENT) < 8) {
            __builtin_amdgcn_s_sleep(8);
            if (++it > (1 << 22)) break;         // bail -> visible failure, not hang
        }
    }

    const bool is_act = (ln < 32);               // act lane: batch=wv, unit=ln
    float c = 0.f;
    float4 gpend = make_float4(0.f, 0.f, 0.f, 0.f);
    const float* Gd = G + (size_t)dir * 8192 * NG_;
    int gok = 1, gready = 0;                     // gp validity + highest known-ready by
    if (is_act) {
        c = c0[(dir * B_ + bt * 8 + wv) * HD_ + ut * 32 + ln];
        gpend = ((const float4*)(Gd + (size_t)(bt * 8 + wv) * NG_))[ut * 32 + ln];
    }

    float* hexg = hex + (size_t)(dir * 4 + bt) * T_ * 2048;  // [t][b*256+u]
    float4* hsX4 = bh ? hsB4 : hsA4;
    float* hsX = (float*)hsX4;

    f4_t pend;                                   // pre-issued poll data

    for (int t = 0; t < Tmax; ++t) {
        // ---- stage h(t-1) slice (wave-private region of hsX) ----
        float4 hv;
        if (t == 0) {
            hv = *(const float4*)(h0 + (size_t)(dir * B_ + bt * 8 + sb) * HD_ + sk);
        } else if (speer == ut) {
            hv = hT4[sb * 8 + ((sk & 31) >> 2)];         // own slice from LDS
        } else {
            asm volatile("s_waitcnt vmcnt(0)" ::: "memory");
            hv.x = pend.x; hv.y = pend.y; hv.z = pend.z; hv.w = pend.w;
            if (__float_as_uint(hv.x) == MAGICU || __float_as_uint(hv.y) == MAGICU ||
                __float_as_uint(hv.z) == MAGICU || __float_as_uint(hv.w) == MAGICU) {
                const float* src = hexg + (size_t)(t - 1) * 2048 + sb * 256 + sk;
                int it = 0;
                for (;;) {
                    __builtin_amdgcn_s_sleep(1);
                    float a0 = __hip_atomic_load(src + 0, __ATOMIC_RELAXED, __HIP_MEMORY_SCOPE_AGENT);
                    float a1 = __hip_atomic_load(src + 1, __ATOMIC_RELAXED, __HIP_MEMORY_SCOPE_AGENT);
                    float a2 = __hip_atomic_load(src + 2, __ATOMIC_RELAXED, __HIP_MEMORY_SCOPE_AGENT);
                    float a3 = __hip_atomic_load(src + 3, __ATOMIC_RELAXED, __HIP_MEMORY_SCOPE_AGENT);
                    if (!(__float_as_uint(a0) == MAGICU || __float_as_uint(a1) == MAGICU ||
                          __float_as_uint(a2) == MAGICU || __float_as_uint(a3) == MAGICU)) {
                        hv = make_float4(a0, a1, a2, a3); break;
                    }
                    if (++it > (1 << 22)) break;   // bail -> visible failure, not hang
                }
            }
        }
        // transpose into [k][4b-half] (wave-private rows)
        hsX[(sk + 0) * 4 + (ln & 3)] = hv.x;
        hsX[(sk + 1) * 4 + (ln & 3)] = hv.y;
        hsX[(sk + 2) * 4 + (ln & 3)] = hv.z;
        hsX[(sk + 3) * 4 + (ln & 3)] = hv.w;
        asm volatile("s_waitcnt lgkmcnt(0)" ::: "memory");   // wave-local visibility

        // ---- FMA: 2 units x 4 gates x 4 batches x 16 k, W in regs ----
        float4 ae0 = {0,0,0,0}, ae1 = {0,0,0,0}, ae2 = {0,0,0,0}, ae3 = {0,0,0,0};
        float4 ao0 = {0,0,0,0}, ao1 = {0,0,0,0}, ao2 = {0,0,0,0}, ao3 = {0,0,0,0};
#pragma unroll
        for (int j = 0; j < 16; ++j) {
            float4 h4 = hsX4[ks * 16 + j];        // h[k][4b of this half]
            float4 we = We[j], wo = Wo[j];
            ae0.x += we.x*h4.x; ae0.y += we.y*h4.x; ae0.z += we.z*h4.x; ae0.w += we.w*h4.x;
            ae1.x += we.x*h4.y; ae1.y += we.y*h4.y; ae1.z += we.z*h4.y; ae1.w += we.w*h4.y;
            ae2.x += we.x*h4.z; ae2.y += we.y*h4.z; ae2.z += we.z*h4.z; ae2.w += we.w*h4.z;
            ae3.x += we.x*h4.w; ae3.y += we.y*h4.w; ae3.z += we.z*h4.w; ae3.w += we.w*h4.w;
            ao0.x += wo.x*h4.x; ao0.y += wo.y*h4.x; ao0.z += wo.z*h4.x; ao0.w += wo.w*h4.x;
            ao1.x += wo.x*h4.y; ao1.y += wo.y*h4.y; ao1.z += wo.z*h4.y; ao1.w += wo.w*h4.y;
            ao2.x += wo.x*h4.z; ao2.y += wo.y*h4.z; ao2.z += wo.z*h4.z; ao2.w += wo.w*h4.z;
            ao3.x += wo.x*h4.w; ao3.y += wo.y*h4.w; ao3.z += wo.z*h4.w; ao3.w += wo.w*h4.w;
        }
        // ---- write partials: row = (wv*4+kssub)*16 + upair, slot = par*4 + b ----
        {
            float4* r = &red4[((wv * 4 + kssub) * 16 + upair) * 11 + kssub];
            r[0] = ae0; r[1] = ae1; r[2] = ae2; r[3] = ae3;
            r[4] = ao0; r[5] = ao1; r[6] = ao2; r[7] = ao3;
        }
        asm volatile("s_waitcnt lgkmcnt(0)\n\ts_barrier" ::: "memory");   // barrier 1

        // ---- act: lane<32 of wave wv handles (batch=wv, unit=ln) ----
        if (is_act) {
            const int b = wv, u = ln;
            const int bhv = b >> 2, bq = b & 3, up = u >> 1, par = u & 1;
            if (!gok) {                           // gp for this step not validated: poll + LLC reload
                const int byc = t >> 2;
                int itc = 0;
                while (__hip_atomic_load(gcnt + dir * 64 + byc, __ATOMIC_RELAXED,
                                         __HIP_MEMORY_SCOPE_AGENT) < 8) {
                    __builtin_amdgcn_s_sleep(2);
                    if (++itc > (1 << 22)) break;
                }
                const float* gsrc = Gd + ((size_t)t * B_ + bt * 8 + b) * NG_ + (size_t)(ut * 32 + u) * 4;
                f4_t tmp;
                asm volatile("global_load_dwordx4 %0, %1, off sc0 sc1\n\ts_waitcnt vmcnt(0)"
                             : "=v"(tmp) : "v"(gsrc) : "memory");
                gpend = make_float4(tmp.x, tmp.y, tmp.z, tmp.w);
            }
            float si = gpend.x, sf = gpend.y, sg = gpend.z, so = gpend.w;
#pragma unroll
            for (int kq = 0; kq < 4; ++kq)
#pragma unroll
                for (int kr = 0; kr < 4; ++kr) {
                    float4 p = red4[(((kq * 2 + bhv) * 4 + kr) * 16 + up) * 11 + kr + par * 4 + bq];
                    si += p.x; sf += p.y; sg += p.z; so += p.w;
                }
            c = sigf(sf) * c + sigf(si) * tanhf(sg);
            float h = sigf(so) * tanhf(c);
            ((float*)hT4)[b * 32 + u] = h;
            // publish: one contiguous 128B segment per wave, agent-coherent
            float* dst = hexg + (size_t)t * 2048 + b * 256 + ut * 32 + u;
            asm volatile("global_store_dword %0, %1, off sc0 sc1" :: "v"(dst), "v"(h) : "memory");
            if (t + 1 < Tmax) {                   // gated prefetch for t+1
                const int byn = (t + 1) >> 2;
                if (byn > gready) {
                    int la = byn + 7; if (la > 63) la = 63;
                    if (__hip_atomic_load(gcnt + dir * 64 + la, __ATOMIC_RELAXED,
                                          __HIP_MEMORY_SCOPE_AGENT) >= 8) gready = la;
                    else if (__hip_atomic_load(gcnt + dir * 64 + byn, __ATOMIC_RELAXED,
                                               __HIP_MEMORY_SCOPE_AGENT) >= 8) gready = byn;
                }
                if (byn <= gready) {
                    gpend = ((const float4*)(Gd + ((size_t)(t + 1) * B_ + bt * 8 + b) * NG_))[ut * 32 + u];
                    gok = 1;
                } else gok = 0;                   // skip -> no stale L2 pull; reload next step
            }
        }
        // ---- pre-issue next step's poll (flight overlaps barrier + peer publish) ----
        if (t + 1 < Tmax && speer != ut) {
            const float* nsrc = hexg + (size_t)t * 2048 + sb * 256 + sk;
            asm volatile("global_load_dwordx4 %0, %1, off sc0 sc1"
                         : "=v"(pend) : "v"(nsrc) : "memory");
        }
        asm volatile("s_waitcnt lgkmcnt(0)\n\ts_barrier" ::: "memory");   // barrier 2
    }
}

// ---------- features from hex: feats[b*T+t][k] = hcat . W_out[k] + b_out[k] ----------
__global__ void feat_k(const float* __restrict__ hex, const int* __restrict__ lens,
                       const float* __restrict__ Wout, const float* __restrict__ bout,
                       float* __restrict__ feats) {
    int tid = threadIdx.x;                 // 192 = 16 pos x 12 tags
    int pl = tid / 12, k = tid % 12;
    int p = blockIdx.x * 16 + pl;          // p = b*256 + t
    int b = p >> 8, t = p & 255;
    int len = lens[b];
    int tr = t < len ? len - 1 - t : t;    // bwd un-reversal (packed semantics)
    const float4* hf = (const float4*)(hex + ((size_t)(b >> 3) * T_ + t) * 2048 + (b & 7) * 256);
    const float4* hb = (const float4*)(hex + ((size_t)(4 + (b >> 3)) * T_ + tr) * 2048 + (b & 7) * 256);
    const float4* w0 = (const float4*)(Wout + (size_t)k * 512);
    const float4* w1 = (const float4*)(Wout + (size_t)k * 512 + 256);
    float acc = bout[k];
#pragma unroll 4
    for (int j = 0; j < 64; ++j) {
        float4 h4 = hf[j], v4 = w0[j];
        acc += h4.x * v4.x + h4.y * v4.y + h4.z * v4.z + h4.w * v4.w;
    }
#pragma unroll 4
    for (int j = 0; j < 64; ++j) {
        float4 h4 = hb[j], v4 = w1[j];
        acc += h4.x * v4.x + h4.y * v4.y + h4.z * v4.z + h4.w * v4.w;
    }
    feats[(size_t)p * K_ + k] = acc;
}

// ---------- Viterbi + backtrace: single block, feats prefetch, bp nibble-packed ----------
__global__ __launch_bounds__(512) void viterbi_k(
    const float* __restrict__ feats, const float* __restrict__ trans,
    const int* __restrict__ lens, float* __restrict__ out) {
    __shared__ float fv[2][B_][16];
    __shared__ float tl[K_][16];
    __shared__ unsigned char bp[T_][B_][6];    // 4-bit backpointers, 48KB
    __shared__ int best_last[B_];
    int tid = threadIdx.x;
    int b = tid >> 4, lane = tid & 15;
    if (tid < K_ * K_) tl[tid / 12][tid % 12] = trans[tid];
    if (lane < K_) fv[0][b][lane] = (lane == START_) ? 0.f : NEG_;
    __syncthreads();
    int len = lens[b];
    int pp = 0;
    float f_cur = 0.f;
    if (lane < K_) f_cur = feats[(size_t)b * T_ * K_ + lane];
    for (int t = 0; t < T_; ++t) {
        float f_nxt = 0.f;                       // prefetch t+1 before the compute chain
        if (t + 1 < T_ && lane < K_) f_nxt = feats[((size_t)b * T_ + t + 1) * K_ + lane];
        if (lane < K_) {
            float best = fv[pp][b][0] + tl[lane][0];
            int argp = 0;
#pragma unroll
            for (int p = 1; p < K_; ++p) {
                float v = fv[pp][b][p] + tl[lane][p];
                if (v > best) { best = v; argp = p; }   // strict > = first-max (matches jnp.argmax)
            }
            float nb = best + f_cur;
            fv[pp ^ 1][b][lane] = (t < len) ? nb : fv[pp][b][lane];
            int other = __shfl_xor(argp, 1);
            if ((lane & 1) == 0) bp[t][b][lane >> 1] = (unsigned char)(argp | (other << 4));
        }
        __syncthreads();
        pp ^= 1;
        f_cur = f_nxt;
    }
    if (lane == 0) {
        float best = fv[pp][b][0] + tl[STOP_][0];
        int bl = 0;
#pragma unroll
        for (int p = 1; p < K_; ++p) {
            float v = fv[pp][b][p] + tl[STOP_][p];
            if (v > best) { best = v; bl = p; }
        }
        out[b] = best;
        best_last[b] = bl;
    }
    __syncthreads();
    if (lane == 0) {
        int tag = best_last[b];
        for (int t = T_ - 1; t >= 0; --t) {
            int m = (t < len);
            out[B_ + b * T_ + t] = (float)(m ? tag : -1);
            if (m) tag = (bp[t][b][tag >> 1] >> ((tag & 1) * 4)) & 15;
        }
    }
}

extern "C" void kernel_launch(void* const* d_in, const int* in_sizes, int n_in,
                              void* d_out, int out_size, void* d_ws, size_t ws_size,
                              hipStream_t stream) {
    const int*   sent  = (const int*)d_in[0];
    const int*   lens  = (const int*)d_in[1];
    const float* emb   = (const float*)d_in[2];
    const float* Wih_f = (const float*)d_in[3];
    const float* Whh_f = (const float*)d_in[4];
    const float* bih_f = (const float*)d_in[5];
    const float* bhh_f = (const float*)d_in[6];
    const float* Wih_b = (const float*)d_in[7];
    const float* Whh_b = (const float*)d_in[8];
    const float* bih_b = (const float*)d_in[9];
    const float* bhh_b = (const float*)d_in[10];
    const float* h0    = (const float*)d_in[11];
    const float* c0    = (const float*)d_in[12];
    const float* Wout  = (const float*)d_in[13];
    const float* bout  = (const float*)d_in[14];
    const float* trans = (const float*)d_in[15];
    float* out = (float*)d_out;

    char* ws = (char*)d_ws;
    int*   tokA  = (int*)ws;                                  // 64 KB
    float* WhhT  = (float*)(ws + 65536);                      // 2 MB
    float* G     = (float*)(ws + 2162688);                    // 67.1 MB
    float* feats = (float*)(ws + 69271552);                   // 0.39 MB
    float* hex   = (float*)(ws + 69664768);                   // 16 MB  [8 groups][T][2048]
    int*   gcnt  = (int*)feats;                               // 512 B, dead before feat_k writes

    prep<<<4672, 256, 0, stream>>>(sent, lens, tokA, Whh_f, Whh_b, WhhT, hex, gcnt);
    mega<<<1088, 512, 0, stream>>>(emb, tokA, Wih_f, Wih_b, bih_f, bhh_f, bih_b, bhh_b,
                                   WhhT, G, h0, c0, lens, hex, gcnt);
    feat_k<<<512, 192, 0, stream>>>(hex, lens, Wout, bout, feats);
    viterbi_k<<<1, 512, 0, stream>>>(feats, trans, lens, out);
}

// Round 8
// 1103.056 us; speedup vs baseline: 1.4830x; 1.0084x over previous
//
#include <hip/hip_runtime.h>
#include <math.h>

#define T_ 256
#define B_ 32
#define E_ 256
#define HD_ 256
#define NG_ 1024
#define K_ 12
#define START_ 10
#define STOP_ 11
#define NEG_ -10000.0f
#define MAGICU 0x40000000u   // 2.0f — |h|<1 so h can never be this bit pattern

typedef float f4_t __attribute__((ext_vector_type(4)));

__device__ __forceinline__ float sigf(float x) { return 1.0f / (1.0f + expf(-x)); }

// ---------- fused prep: hex sentinel fill + Whh^T + token gather + gcnt zero ----------
__global__ void prep(const int* __restrict__ sent, const int* __restrict__ lens,
                     int* __restrict__ tokA, const float* __restrict__ Wf,
                     const float* __restrict__ Wb, float* __restrict__ WT,
                     float* __restrict__ hex, int* __restrict__ gcnt) {
    const int b = blockIdx.x, tid = threadIdx.x;
    if (b < 4096) {
        // hex sentinel fill: 4096 blocks x 256 thr x 16 B = 16 MB
        float4 m = make_float4(2.0f, 2.0f, 2.0f, 2.0f);
        ((float4*)hex)[b * 256 + tid] = m;
        if (b == 0 && tid < 128) gcnt[tid] = 0;   // gcnt lives in d_out preds region
    } else if (b < 4608) {
        // Whh^T into [dir][k][u*4+gate] (unit-major gate packing)
        int b2 = b - 4096;
        int dir = b2 >> 8, k = b2 & 255, u = tid;
        const float* W = dir ? Wb : Wf;
        float4 v;
        v.x = W[(0 * HD_ + u) * HD_ + k];   // i
        v.y = W[(1 * HD_ + u) * HD_ + k];   // f
        v.z = W[(2 * HD_ + u) * HD_ + k];   // g
        v.w = W[(3 * HD_ + u) * HD_ + k];   // o
        ((float4*)(WT + ((size_t)dir * 256 + k) * NG_))[u] = v;
    } else {
        // token gather (bwd dir reversed within each sequence length)
        int e = (b - 4608) * 256 + tid;      // 0..16383 = [dir][t*32+b]
        int dir = e >> 13, m = e & 8191, t = m >> 5, bb = m & 31;
        int len = lens[bb];
        int tt = dir ? (t < len ? len - 1 - t : t) : t;
        tokA[e] = sent[bb * T_ + tt];
    }
}

// ---------- mega-kernel, 3 roles by blockIdx (r6 protocol, fences reverted):
//   [0,64)      v11 lstm recurrence (proven exchange, gcnt-gated G prefetch,
//               RELAXED gcnt polls — NO acquire: agent-acquire = cache-WIDE inv)
//   [64,1088)   in_gemm producers: sc0 sc1 write-through G stores + vmcnt(0)
//               drain + barrier + atomicAdd release (r6-proven; r7's plain-store
//               + __threadfence (full-L2 wbl2) variant killed the container)
//   [1088,1344) feat blocks: RELAXED agent atomic polls of hex with s_sleep+bail
//               (the identical h-exchange idiom); skip retry for t >= Tmax_group
//               (legit sentinels, masked downstream); LDS stage, 12-tag dots.
// Dispatch order lstm -> producers -> feat matches dependency order; lstm CUs
// are resident from t=0 so feat spins cannot starve progress. No hang possible.
__global__ __launch_bounds__(512, 1) void mega(
    const float* __restrict__ emb, const int* __restrict__ tokA,
    const float* __restrict__ Wih_f, const float* __restrict__ Wih_b,
    const float* __restrict__ bih_f, const float* __restrict__ bhh_f,
    const float* __restrict__ bih_b, const float* __restrict__ bhh_b,
    const float* __restrict__ WhhT, float* __restrict__ G,
    const float* __restrict__ h0, const float* __restrict__ c0,
    const int* __restrict__ lens, float* __restrict__ hex,
    int* __restrict__ gcnt, const float* __restrict__ Wout,
    const float* __restrict__ bout, float* __restrict__ feats) {
    __shared__ float smem[24832];                // 99328 B, carved per role
    const int tid = threadIdx.x;

    if (blockIdx.x >= 1088) {
        // ================= feat role: 256 blocks x 32 positions =================
        const int blk = blockIdx.x - 1088;
        f4_t* hbuf = (f4_t*)smem;                // [32][129] f4 (pad kills bank conflicts)
#pragma unroll
        for (int i = 0; i < 8; ++i) {
            int idx = i * 512 + tid;             // 0..4095 = [pos 0..31][j 0..127]
            int pl = idx >> 7, j = idx & 127;
            int p = blk * 32 + pl;
            int b = p >> 8, t = p & 255;
            int len = lens[b];
            int g = b >> 3;
            int Tg = lens[g * 8];                // group Tmax (lens sorted desc)
            const float* addr;
            if (j < 64) {                        // fwd h at t
                addr = hex + ((size_t)g * T_ + t) * 2048 + (b & 7) * 256 + j * 4;
            } else {                             // bwd h at un-reversed index
                int tr = t < len ? len - 1 - t : t;
                addr = hex + ((size_t)(4 + g) * T_ + tr) * 2048 + (b & 7) * 256 + (j - 64) * 4;
            }
            float a0 = __hip_atomic_load(addr + 0, __ATOMIC_RELAXED, __HIP_MEMORY_SCOPE_AGENT);
            float a1 = __hip_atomic_load(addr + 1, __ATOMIC_RELAXED, __HIP_MEMORY_SCOPE_AGENT);
            float a2 = __hip_atomic_load(addr + 2, __ATOMIC_RELAXED, __HIP_MEMORY_SCOPE_AGENT);
            float a3 = __hip_atomic_load(addr + 3, __ATOMIC_RELAXED, __HIP_MEMORY_SCOPE_AGENT);
            if (t < Tg) {                        // real data coming: retry until non-magic
                int it = 0;
                while (__float_as_uint(a0) == MAGICU || __float_as_uint(a1) == MAGICU ||
                       __float_as_uint(a2) == MAGICU || __float_as_uint(a3) == MAGICU) {
                    __builtin_amdgcn_s_sleep(2);
                    a0 = __hip_atomic_load(addr + 0, __ATOMIC_RELAXED, __HIP_MEMORY_SCOPE_AGENT);
                    a1 = __hip_atomic_load(addr + 1, __ATOMIC_RELAXED, __HIP_MEMORY_SCOPE_AGENT);
                    a2 = __hip_atomic_load(addr + 2, __ATOMIC_RELAXED, __HIP_MEMORY_SCOPE_AGENT);
                    a3 = __hip_atomic_load(addr + 3, __ATOMIC_RELAXED, __HIP_MEMORY_SCOPE_AGENT);
                    if (++it > (1 << 22)) break; // bail -> visible failure, not hang
                }
            }
            f4_t v; v.x = a0; v.y = a1; v.z = a2; v.w = a3;
            hbuf[pl * 129 + j] = v;
        }
        __syncthreads();
        if (tid < 384) {
            int pl = tid / 12, k = tid - pl * 12;
            int p = blk * 32 + pl;
            const float4* w0 = (const float4*)(Wout + (size_t)k * 512);
            const f4_t* hrow = hbuf + pl * 129;
            float acc = bout[k];
#pragma unroll 4
            for (int j = 0; j < 128; ++j) {
                f4_t h4 = hrow[j];
                float4 v4 = w0[j];
                acc += h4.x * v4.x + h4.y * v4.y + h4.z * v4.z + h4.w * v4.w;
            }
            feats[(size_t)p * K_ + k] = acc;
        }
        return;
    }

    if (blockIdx.x >= 64) {
        // ================= in_gemm role (512 threads, 128x128 tile) =================
        const int bi = blockIdx.x - 64;
        const int by = bi >> 4, sub = bi & 15;   // by-major order -> early t-tiles first
        const int dir = sub >> 3, bx = sub & 7;
        const int n0 = bx * 128, m0 = by * 128;
        float* As = smem;                        // [8][128]
        float* Bs = smem + 1024;                 // [8][128]
        const int rs = (tid & 255) >> 1, kc = (tid & 1) * 4;
        const float* srow;
        if (tid < 256) {
            int tok = tokA[dir * 8192 + m0 + rs];
            srow = emb + (size_t)tok * E_;
        } else {
            int np = n0 + rs;
            int wrow = ((np & 3) << 8) | (np >> 2);   // permuted col n'=u*4+g -> Wih row g*256+u
            srow = (dir ? Wih_b : Wih_f) + (size_t)wrow * E_;
        }
        float* Ls = (tid < 256) ? As : Bs;
        const int ty = tid >> 4, tx = tid & 15;  // ty 0..31 (4 rows), tx 0..15 (8 cols)

        float acc[4][8];
#pragma unroll
        for (int i = 0; i < 4; ++i)
#pragma unroll
            for (int j = 0; j < 8; ++j) acc[i][j] = 0.f;

        for (int k0 = 0; k0 < E_; k0 += 8) {
            float4 v = *(const float4*)(srow + k0 + kc);
            __syncthreads();
            Ls[(kc + 0) * 128 + rs] = v.x;
            Ls[(kc + 1) * 128 + rs] = v.y;
            Ls[(kc + 2) * 128 + rs] = v.z;
            Ls[(kc + 3) * 128 + rs] = v.w;
            __syncthreads();
#pragma unroll
            for (int k = 0; k < 8; ++k) {
                float4 a  = *(const float4*)&As[k * 128 + ty * 4];
                float4 b0 = *(const float4*)&Bs[k * 128 + tx * 8];
                float4 b1 = *(const float4*)&Bs[k * 128 + tx * 8 + 4];
                float af[4] = {a.x, a.y, a.z, a.w};
                float bf[8] = {b0.x, b0.y, b0.z, b0.w, b1.x, b1.y, b1.z, b1.w};
#pragma unroll
                for (int i = 0; i < 4; ++i)
#pragma unroll
                    for (int j = 0; j < 8; ++j) acc[i][j] += af[i] * bf[j];
            }
        }
        const float* bihp = dir ? bih_b : bih_f;
        const float* bhhp = dir ? bhh_b : bhh_f;
        float bias[8];
#pragma unroll
        for (int j = 0; j < 8; ++j) {
            int nn = n0 + tx * 8 + j;
            int wr = ((nn & 3) << 8) | (nn >> 2);
            bias[j] = bihp[wr] + bhhp[wr];
        }
#pragma unroll
        for (int i = 0; i < 4; ++i) {
            int m = m0 + ty * 4 + i;
            float* gp = G + ((size_t)dir * 8192 + m) * NG_ + n0 + tx * 8;
            f4_t o0, o1;
            o0.x = acc[i][0] + bias[0]; o0.y = acc[i][1] + bias[1];
            o0.z = acc[i][2] + bias[2]; o0.w = acc[i][3] + bias[3];
            o1.x = acc[i][4] + bias[4]; o1.y = acc[i][5] + bias[5];
            o1.z = acc[i][6] + bias[6]; o1.w = acc[i][7] + bias[7];
            asm volatile("global_store_dwordx4 %0, %1, off sc0 sc1" :: "v"(gp), "v"(o0) : "memory");
            asm volatile("global_store_dwordx4 %0, %1, off sc0 sc1" :: "v"(gp + 4), "v"(o1) : "memory");
        }
        asm volatile("s_waitcnt vmcnt(0)" ::: "memory");
        __syncthreads();
        if (tid == 0)
            __hip_atomic_fetch_add(gcnt + dir * 64 + by, 1,
                                   __ATOMIC_RELEASE, __HIP_MEMORY_SCOPE_AGENT);
        return;
    }

    // ================= lstm role: v11 verbatim + G-counter gating =================
    float4* red4 = (float4*)smem;                // 512*11 f4 (90112 B)
    float4* hsA4 = (float4*)(smem + 22528);      // 256 f4: h[k][b0..3]
    float4* hsB4 = (float4*)(smem + 23552);      // 256 f4: h[k][b4..7]
    float4* hT4  = (float4*)(smem + 24576);      // 64 f4: own h [b][32u]

    const int wg = blockIdx.x;                   // dir*32 + bt*8 + ut
    const int dir = wg >> 5, bt = (wg >> 3) & 3, ut = wg & 7;
    const int wv = tid >> 6, ln = tid & 63;
    const int upair = ln & 15;
    const int kssub = ln >> 4;
    const int ksup = wv >> 1, bh = wv & 1;
    const int ks = ksup * 4 + kssub;
    const int sb = bh * 4 + (ln & 3);
    const int sk = ksup * 64 + (ln >> 2) * 4;
    const int speer = sk >> 5;

    const int Tmax = lens[bt * 8];               // lens sorted desc -> group max

    // ---- W into registers: 32 f4/thread ----
    const float4* WT4 = (const float4*)(WhhT + (size_t)dir * 256 * NG_);
    const int gu_e = ut * 32 + upair * 2;
    float4 We[16], Wo[16];
#pragma unroll
    for (int j = 0; j < 16; ++j) {
        We[j] = WT4[(ks * 16 + j) * 256 + gu_e];
        Wo[j] = WT4[(ks * 16 + j) * 256 + gu_e + 1];
    }

    // ---- wait for G tile by=0 (t=0..3) before the initial gp load ----
    {
        int it = 0;
        while (__hip_atomic_load(gcnt + dir * 64, __ATOMIC_RELAXED, __HIP_MEMORY_SCOPE_AGENT) < 8) {
            __builtin_amdgcn_s_sleep(8);
            if (++it > (1 << 22)) break;         // bail -> visible failure, not hang
        }
    }

    const bool is_act = (ln < 32);               // act lane: batch=wv, unit=ln
    float c = 0.f;
    float4 gpend = make_float4(0.f, 0.f, 0.f, 0.f);
    const float* Gd = G + (size_t)dir * 8192 * NG_;
    int gok = 1, gready = 0;                     // gp validity + highest known-ready by
    if (is_act) {
        c = c0[(dir * B_ + bt * 8 + wv) * HD_ + ut * 32 + ln];
        gpend = ((const float4*)(Gd + (size_t)(bt * 8 + wv) * NG_))[ut * 32 + ln];
    }

    float* hexg = hex + (size_t)(dir * 4 + bt) * T_ * 2048;  // [t][b*256+u]
    float4* hsX4 = bh ? hsB4 : hsA4;
    float* hsX = (float*)hsX4;

    f4_t pend;                                   // pre-issued poll data

    for (int t = 0; t < Tmax; ++t) {
        // ---- stage h(t-1) slice (wave-private region of hsX) ----
        float4 hv;
        if (t == 0) {
            hv = *(const float4*)(h0 + (size_t)(dir * B_ + bt * 8 + sb) * HD_ + sk);
        } else if (speer == ut) {
            hv = hT4[sb * 8 + ((sk & 31) >> 2)];         // own slice from LDS
        } else {
            asm volatile("s_waitcnt vmcnt(0)" ::: "memory");
            hv.x = pend.x; hv.y = pend.y; hv.z = pend.z; hv.w = pend.w;
            if (__float_as_uint(hv.x) == MAGICU || __float_as_uint(hv.y) == MAGICU ||
                __float_as_uint(hv.z) == MAGICU || __float_as_uint(hv.w) == MAGICU) {
                const float* src = hexg + (size_t)(t - 1) * 2048 + sb * 256 + sk;
                int it = 0;
                for (;;) {
                    __builtin_amdgcn_s_sleep(1);
                    float a0 = __hip_atomic_load(src + 0, __ATOMIC_RELAXED, __HIP_MEMORY_SCOPE_AGENT);
                    float a1 = __hip_atomic_load(src + 1, __ATOMIC_RELAXED, __HIP_MEMORY_SCOPE_AGENT);
                    float a2 = __hip_atomic_load(src + 2, __ATOMIC_RELAXED, __HIP_MEMORY_SCOPE_AGENT);
                    float a3 = __hip_atomic_load(src + 3, __ATOMIC_RELAXED, __HIP_MEMORY_SCOPE_AGENT);
                    if (!(__float_as_uint(a0) == MAGICU || __float_as_uint(a1) == MAGICU ||
                          __float_as_uint(a2) == MAGICU || __float_as_uint(a3) == MAGICU)) {
                        hv = make_float4(a0, a1, a2, a3); break;
                    }
                    if (++it > (1 << 22)) break;   // bail -> visible failure, not hang
                }
            }
        }
        // transpose into [k][4b-half] (wave-private rows)
        hsX[(sk + 0) * 4 + (ln & 3)] = hv.x;
        hsX[(sk + 1) * 4 + (ln & 3)] = hv.y;
        hsX[(sk + 2) * 4 + (ln & 3)] = hv.z;
        hsX[(sk + 3) * 4 + (ln & 3)] = hv.w;
        asm volatile("s_waitcnt lgkmcnt(0)" ::: "memory");   // wave-local visibility

        // ---- FMA: 2 units x 4 gates x 4 batches x 16 k, W in regs ----
        float4 ae0 = {0,0,0,0}, ae1 = {0,0,0,0}, ae2 = {0,0,0,0}, ae3 = {0,0,0,0};
        float4 ao0 = {0,0,0,0}, ao1 = {0,0,0,0}, ao2 = {0,0,0,0}, ao3 = {0,0,0,0};
#pragma unroll
        for (int j = 0; j < 16; ++j) {
            float4 h4 = hsX4[ks * 16 + j];        // h[k][4b of this half]
            float4 we = We[j], wo = Wo[j];
            ae0.x += we.x*h4.x; ae0.y += we.y*h4.x; ae0.z += we.z*h4.x; ae0.w += we.w*h4.x;
            ae1.x += we.x*h4.y; ae1.y += we.y*h4.y; ae1.z += we.z*h4.y; ae1.w += we.w*h4.y;
            ae2.x += we.x*h4.z; ae2.y += we.y*h4.z; ae2.z += we.z*h4.z; ae2.w += we.w*h4.z;
            ae3.x += we.x*h4.w; ae3.y += we.y*h4.w; ae3.z += we.z*h4.w; ae3.w += we.w*h4.w;
            ao0.x += wo.x*h4.x; ao0.y += wo.y*h4.x; ao0.z += wo.z*h4.x; ao0.w += wo.w*h4.x;
            ao1.x += wo.x*h4.y; ao1.y += wo.y*h4.y; ao1.z += wo.z*h4.y; ao1.w += wo.w*h4.y;
            ao2.x += wo.x*h4.z; ao2.y += wo.y*h4.z; ao2.z += wo.z*h4.z; ao2.w += wo.w*h4.z;
            ao3.x += wo.x*h4.w; ao3.y += wo.y*h4.w; ao3.z += wo.z*h4.w; ao3.w += wo.w*h4.w;
        }
        // ---- write partials: row = (wv*4+kssub)*16 + upair, slot = par*4 + b ----
        {
            float4* r = &red4[((wv * 4 + kssub) * 16 + upair) * 11 + kssub];
            r[0] = ae0; r[1] = ae1; r[2] = ae2; r[3] = ae3;
            r[4] = ao0; r[5] = ao1; r[6] = ao2; r[7] = ao3;
        }
        asm volatile("s_waitcnt lgkmcnt(0)\n\ts_barrier" ::: "memory");   // barrier 1

        // ---- act: lane<32 of wave wv handles (batch=wv, unit=ln) ----
        if (is_act) {
            const int b = wv, u = ln;
            const int bhv = b >> 2, bq = b & 3, up = u >> 1, par = u & 1;
            if (!gok) {                           // gp for this step not validated: poll + LLC reload
                const int byc = t >> 2;
                int itc = 0;
                while (__hip_atomic_load(gcnt + dir * 64 + byc, __ATOMIC_RELAXED,
                                         __HIP_MEMORY_SCOPE_AGENT) < 8) {
                    __builtin_amdgcn_s_sleep(2);
                    if (++itc > (1 << 22)) break;
                }
                const float* gsrc = Gd + ((size_t)t * B_ + bt * 8 + b) * NG_ + (size_t)(ut * 32 + u) * 4;
                f4_t tmp;
                asm volatile("global_load_dwordx4 %0, %1, off sc0 sc1\n\ts_waitcnt vmcnt(0)"
                             : "=v"(tmp) : "v"(gsrc) : "memory");
                gpend = make_float4(tmp.x, tmp.y, tmp.z, tmp.w);
            }
            float si = gpend.x, sf = gpend.y, sg = gpend.z, so = gpend.w;
#pragma unroll
            for (int kq = 0; kq < 4; ++kq)
#pragma unroll
                for (int kr = 0; kr < 4; ++kr) {
                    float4 p = red4[(((kq * 2 + bhv) * 4 + kr) * 16 + up) * 11 + kr + par * 4 + bq];
                    si += p.x; sf += p.y; sg += p.z; so += p.w;
                }
            c = sigf(sf) * c + sigf(si) * tanhf(sg);
            float h = sigf(so) * tanhf(c);
            ((float*)hT4)[b * 32 + u] = h;
            // publish: one contiguous 128B segment per wave, agent-coherent
            float* dst = hexg + (size_t)t * 2048 + b * 256 + ut * 32 + u;
            asm volatile("global_store_dword %0, %1, off sc0 sc1" :: "v"(dst), "v"(h) : "memory");
            if (t + 1 < Tmax) {                   // gated prefetch for t+1
                const int byn = (t + 1) >> 2;
                if (byn > gready) {
                    int la = byn + 7; if (la > 63) la = 63;
                    if (__hip_atomic_load(gcnt + dir * 64 + la, __ATOMIC_RELAXED,
                                          __HIP_MEMORY_SCOPE_AGENT) >= 8) gready = la;
                    else if (__hip_atomic_load(gcnt + dir * 64 + byn, __ATOMIC_RELAXED,
                                               __HIP_MEMORY_SCOPE_AGENT) >= 8) gready = byn;
                }
                if (byn <= gready) {
                    gpend = ((const float4*)(Gd + ((size_t)(t + 1) * B_ + bt * 8 + b) * NG_))[ut * 32 + u];
                    gok = 1;
                } else gok = 0;                   // skip -> no stale pull; reload next step
            }
        }
        // ---- pre-issue next step's poll (flight overlaps barrier + peer publish) ----
        if (t + 1 < Tmax && speer != ut) {
            const float* nsrc = hexg + (size_t)t * 2048 + sb * 256 + sk;
            asm volatile("global_load_dwordx4 %0, %1, off sc0 sc1"
                         : "=v"(pend) : "v"(nsrc) : "memory");
        }
        asm volatile("s_waitcnt lgkmcnt(0)\n\ts_barrier" ::: "memory");   // barrier 2
    }
}

// ---------- Viterbi + backtrace: single block, feats prefetch, bp nibble-packed ----------
__global__ __launch_bounds__(512) void viterbi_k(
    const float* __restrict__ feats, const float* __restrict__ trans,
    const int* __restrict__ lens, float* __restrict__ out) {
    __shared__ float fv[2][B_][16];
    __shared__ float tl[K_][16];
    __shared__ unsigned char bp[T_][B_][6];    // 4-bit backpointers, 48KB
    __shared__ int best_last[B_];
    int tid = threadIdx.x;
    int b = tid >> 4, lane = tid & 15;
    if (tid < K_ * K_) tl[tid / 12][tid % 12] = trans[tid];
    if (lane < K_) fv[0][b][lane] = (lane == START_) ? 0.f : NEG_;
    __syncthreads();
    int len = lens[b];
    int pp = 0;
    float f_cur = 0.f;
    if (lane < K_) f_cur = feats[(size_t)b * T_ * K_ + lane];
    for (int t = 0; t < T_; ++t) {
        float f_nxt = 0.f;                       // prefetch t+1 before the compute chain
        if (t + 1 < T_ && lane < K_) f_nxt = feats[((size_t)b * T_ + t + 1) * K_ + lane];
        if (lane < K_) {
            float best = fv[pp][b][0] + tl[lane][0];
            int argp = 0;
#pragma unroll
            for (int p = 1; p < K_; ++p) {
                float v = fv[pp][b][p] + tl[lane][p];
                if (v > best) { best = v; argp = p; }   // strict > = first-max (matches jnp.argmax)
            }
            float nb = best + f_cur;
            fv[pp ^ 1][b][lane] = (t < len) ? nb : fv[pp][b][lane];
            int other = __shfl_xor(argp, 1);
            if ((lane & 1) == 0) bp[t][b][lane >> 1] = (unsigned char)(argp | (other << 4));
        }
        __syncthreads();
        pp ^= 1;
        f_cur = f_nxt;
    }
    if (lane == 0) {
        float best = fv[pp][b][0] + tl[STOP_][0];
        int bl = 0;
#pragma unroll
        for (int p = 1; p < K_; ++p) {
            float v = fv[pp][b][p] + tl[STOP_][p];
            if (v > best) { best = v; bl = p; }
        }
        out[b] = best;
        best_last[b] = bl;
    }
    __syncthreads();
    if (lane == 0) {
        int tag = best_last[b];
        for (int t = T_ - 1; t >= 0; --t) {
            int m = (t < len);
            out[B_ + b * T_ + t] = (float)(m ? tag : -1);
            if (m) tag = (bp[t][b][tag >> 1] >> ((tag & 1) * 4)) & 15;
        }
    }
}

extern "C" void kernel_launch(void* const* d_in, const int* in_sizes, int n_in,
                              void* d_out, int out_size, void* d_ws, size_t ws_size,
                              hipStream_t stream) {
    const int*   sent  = (const int*)d_in[0];
    const int*   lens  = (const int*)d_in[1];
    const float* emb   = (const float*)d_in[2];
    const float* Wih_f = (const float*)d_in[3];
    const float* Whh_f = (const float*)d_in[4];
    const float* bih_f = (const float*)d_in[5];
    const float* bhh_f = (const float*)d_in[6];
    const float* Wih_b = (const float*)d_in[7];
    const float* Whh_b = (const float*)d_in[8];
    const float* bih_b = (const float*)d_in[9];
    const float* bhh_b = (const float*)d_in[10];
    const float* h0    = (const float*)d_in[11];
    const float* c0    = (const float*)d_in[12];
    const float* Wout  = (const float*)d_in[13];
    const float* bout  = (const float*)d_in[14];
    const float* trans = (const float*)d_in[15];
    float* out = (float*)d_out;

    char* ws = (char*)d_ws;
    int*   tokA  = (int*)ws;                                  // 64 KB
    float* WhhT  = (float*)(ws + 65536);                      // 2 MB
    float* G     = (float*)(ws + 2162688);                    // 67.1 MB
    float* feats = (float*)(ws + 69271552);                   // 0.39 MB
    float* hex   = (float*)(ws + 69664768);                   // 16 MB  [8 groups][T][2048]
    // gcnt: 128 ints in d_out's preds region (out[32..159]); zeroed by prep,
    // fully overwritten by viterbi_k at the end. feats region is written
    // concurrently by the feat role, so an overlay there would race.
    int*   gcnt  = (int*)(out + 32);

    prep<<<4672, 256, 0, stream>>>(sent, lens, tokA, Whh_f, Whh_b, WhhT, hex, gcnt);
    mega<<<1344, 512, 0, stream>>>(emb, tokA, Wih_f, Wih_b, bih_f, bhh_f, bih_b, bhh_b,
                                   WhhT, G, h0, c0, lens, hex, gcnt, Wout, bout, feats);
    viterbi_k<<<1, 512, 0, stream>>>(feats, trans, lens, out);
}